// Round 1
// baseline (1154.660 us; speedup 1.0000x reference)
//
#include <hip/hip_runtime.h>

// CylinderFeatureEncoder fused kernel: BN -> 4-layer MLP -> voxel scatter-max.
// Compute-bound on f32 vector ALU (no fp32 MFMA on CDNA4). 115 GFLOP total.

constexpr int Bc   = 2;
constexpr int Nc   = 250000;
constexpr int Pc   = Bc * Nc;          // 500000 points
constexpr int Gc   = 64;
constexpr int NSc  = Bc * Gc * Gc * Gc; // 524288 segments
constexpr float EPSV = 1e-5f;

// LDS layout: h[row=feat][col=point], 64 points per block, quad-swizzled:
// quad index cq (col/4) is XORed with (row>>2) so that the epilogue writes
// (16 lanes hitting rows stride-4 apart at the same column quad) spread over
// all 8 LDS quad-bank groups (hits the 8-phase floor for 1KB/instr), while
// k-loop reads stay 4-distinct-quads + 16-lane broadcast (conflict-free).
__device__ __forceinline__ int hq(int row, int cq) {
  return row * 64 + (((cq ^ (row >> 2)) & 15) << 2);
}

// Order-preserving f32 -> u32 encoding for atomic max. 0u is below every
// real encoding (would require bits==0xFFFFFFFF, a NaN) -> init sentinel.
__device__ __forceinline__ unsigned fenc(float f) {
  unsigned b = __float_as_uint(f);
  return (b & 0x80000000u) ? ~b : (b | 0x80000000u);
}
__device__ __forceinline__ unsigned fdec(unsigned u) {
  if (u == 0u) return 0u;  // empty voxel -> 0.0f (matches where(cnt>0,...,0))
  return (u & 0x80000000u) ? (u & 0x7fffffffu) : ~u;
}

__global__ void init_out_kernel(uint4* __restrict__ p, int n4) {
  int i = blockIdx.x * blockDim.x + threadIdx.x;
  const int st = gridDim.x * blockDim.x;
  const uint4 z = make_uint4(0u, 0u, 0u, 0u);
  for (; i < n4; i += st) p[i] = z;
}

__global__ void decode_out_kernel(uint4* __restrict__ p, int n4) {
  int i = blockIdx.x * blockDim.x + threadIdx.x;
  const int st = gridDim.x * blockDim.x;
  for (; i < n4; i += st) {
    uint4 u = p[i];
    u.x = fdec(u.x); u.y = fdec(u.y); u.z = fdec(u.z); u.w = fdec(u.w);
    p[i] = u;
  }
}

#define FMA16(ACC, HV, WV)                          \
  do {                                              \
    ACC[0][0] = fmaf(HV.x, WV.x, ACC[0][0]);        \
    ACC[0][1] = fmaf(HV.x, WV.y, ACC[0][1]);        \
    ACC[0][2] = fmaf(HV.x, WV.z, ACC[0][2]);        \
    ACC[0][3] = fmaf(HV.x, WV.w, ACC[0][3]);        \
    ACC[1][0] = fmaf(HV.y, WV.x, ACC[1][0]);        \
    ACC[1][1] = fmaf(HV.y, WV.y, ACC[1][1]);        \
    ACC[1][2] = fmaf(HV.y, WV.z, ACC[1][2]);        \
    ACC[1][3] = fmaf(HV.y, WV.w, ACC[1][3]);        \
    ACC[2][0] = fmaf(HV.z, WV.x, ACC[2][0]);        \
    ACC[2][1] = fmaf(HV.z, WV.y, ACC[2][1]);        \
    ACC[2][2] = fmaf(HV.z, WV.z, ACC[2][2]);        \
    ACC[2][3] = fmaf(HV.z, WV.w, ACC[2][3]);        \
    ACC[3][0] = fmaf(HV.w, WV.x, ACC[3][0]);        \
    ACC[3][1] = fmaf(HV.w, WV.y, ACC[3][1]);        \
    ACC[3][2] = fmaf(HV.w, WV.z, ACC[3][2]);        \
    ACC[3][3] = fmaf(HV.w, WV.w, ACC[3][3]);        \
  } while (0)

// GEMM: hout[o][p] = relu( (hin^T @ W + bias - m) * g*rsqrt(v+eps) + b ).
// 256 threads = 16(tx: output quads) x 16(ty: point quads); 4x4 register tile.
template<int FI, int FO>
__device__ __forceinline__ void layer_gemm(
    const float* __restrict__ hin, const float* __restrict__ W,
    const float* __restrict__ bias,
    const float* __restrict__ bg, const float* __restrict__ bb,
    const float* __restrict__ bm, const float* __restrict__ bv,
    float* __restrict__ hout, int tx, int ty)
{
  #pragma unroll
  for (int ot = 0; ot < FO / 64; ++ot) {
    const int ob = ot * 64 + tx * 4;
    float acc[4][4];
    #pragma unroll
    for (int j = 0; j < 4; ++j)
      #pragma unroll
      for (int i = 0; i < 4; ++i) acc[j][i] = 0.f;
    #pragma unroll 8
    for (int k = 0; k < FI; ++k) {
      const float4 hv = *(const float4*)(hin + hq(k, ty));      // ds_read_b128
      const float4 wv = *(const float4*)(W + k * FO + ob);      // global dwordx4 (L1/L2 hot)
      FMA16(acc, hv, wv);
    }
    #pragma unroll
    for (int i = 0; i < 4; ++i) {
      const int o = ob + i;
      const float s = bg[o] * rsqrtf(bv[o] + EPSV);
      const float c = fmaf(bias[o] - bm[o], s, bb[o]);
      float4 r;
      r.x = fmaxf(fmaf(acc[0][i], s, c), 0.f);
      r.y = fmaxf(fmaf(acc[1][i], s, c), 0.f);
      r.z = fmaxf(fmaf(acc[2][i], s, c), 0.f);
      r.w = fmaxf(fmaf(acc[3][i], s, c), 0.f);
      *(float4*)(hout + hq(o, ty)) = r;
    }
  }
}

__global__ __launch_bounds__(256, 2)
void fused_mlp_kernel(
    const float* __restrict__ pt_fea, const int* __restrict__ pt_ind,
    const float* __restrict__ g0, const float* __restrict__ bB0,
    const float* __restrict__ m0, const float* __restrict__ v0,
    const float* __restrict__ g1, const float* __restrict__ bB1,
    const float* __restrict__ m1, const float* __restrict__ v1,
    const float* __restrict__ g2, const float* __restrict__ bB2,
    const float* __restrict__ m2, const float* __restrict__ v2,
    const float* __restrict__ g3, const float* __restrict__ bB3,
    const float* __restrict__ m3, const float* __restrict__ v3,
    const float* __restrict__ W0, const float* __restrict__ bb0,
    const float* __restrict__ W1, const float* __restrict__ bb1,
    const float* __restrict__ W2, const float* __restrict__ bb2,
    const float* __restrict__ W3, const float* __restrict__ bb3,
    unsigned* __restrict__ out)
{
  __shared__ float x0[3 * 64];    // BN0-applied input, [c][p]
  __shared__ float hA[64 * 64];   // h1, then reused as h3 64-wide chunks
  __shared__ float hB[128 * 64];  // h2
  __shared__ int seg_s[64];

  const int tid = threadIdx.x;
  const int tx = tid & 15, ty = tid >> 4;
  const int pbase = blockIdx.x * 64;

  // ---- load 64 points, apply BN0, compute segment ids ----
  if (tid < 192) {
    const int lp = tid / 3;
    const int c  = tid - lp * 3;
    const int gp = pbase + lp;
    float val = 0.f;
    if (gp < Pc) {
      const float x = pt_fea[gp * 3 + c];   // == pt_fea[pbase*3 + tid], coalesced
      const float s = g0[c] * rsqrtf(v0[c] + EPSV);
      val = fmaf(x - m0[c], s, bB0[c]);
    }
    x0[c * 64 + lp] = val;
  }
  if (tid < 64) {
    const int gp = pbase + tid;
    int sg = -1;
    if (gp < Pc) {
      const int ix = pt_ind[gp * 3 + 0];
      const int iy = pt_ind[gp * 3 + 1];
      const int iz = pt_ind[gp * 3 + 2];
      const int b  = gp / Nc;
      sg = ((b * Gc + iz) * Gc + iy) * Gc + ix;   // (batch, z, y, x)
    }
    seg_s[tid] = sg;
  }
  __syncthreads();

  // ---- L0: 3 -> 64 (BN1 + relu) ----
  layer_gemm<3, 64>(x0, W0, bb0, g1, bB1, m1, v1, hA, tx, ty);
  __syncthreads();
  // ---- L1: 64 -> 128 (BN2 + relu) ----
  layer_gemm<64, 128>(hA, W1, bb1, g2, bB2, m2, v2, hB, tx, ty);
  __syncthreads();

  // ---- L2 (128->256, BN3+relu) fused with L3 (256->64) in 64-wide chunks ----
  float facc[4][4];
  #pragma unroll
  for (int j = 0; j < 4; ++j)
    #pragma unroll
    for (int i = 0; i < 4; ++i) facc[j][i] = 0.f;

  #pragma unroll 1
  for (int jc = 0; jc < 4; ++jc) {
    const int ob = jc * 64 + tx * 4;   // layer-2 output features of this chunk
    float acc[4][4];
    #pragma unroll
    for (int j = 0; j < 4; ++j)
      #pragma unroll
      for (int i = 0; i < 4; ++i) acc[j][i] = 0.f;
    #pragma unroll 4
    for (int k = 0; k < 128; ++k) {
      const float4 hv = *(const float4*)(hB + hq(k, ty));
      const float4 wv = *(const float4*)(W2 + k * 256 + ob);
      FMA16(acc, hv, wv);
    }
    __syncthreads();   // previous chunk (or h1) fully consumed before overwrite
    #pragma unroll
    for (int i = 0; i < 4; ++i) {
      const int o  = ob + i;       // global layer-2 feature
      const int lr = tx * 4 + i;   // local chunk row
      const float s = g3[o] * rsqrtf(v3[o] + EPSV);
      const float c = fmaf(bb2[o] - m3[o], s, bB3[o]);
      float4 r;
      r.x = fmaxf(fmaf(acc[0][i], s, c), 0.f);
      r.y = fmaxf(fmaf(acc[1][i], s, c), 0.f);
      r.z = fmaxf(fmaf(acc[2][i], s, c), 0.f);
      r.w = fmaxf(fmaf(acc[3][i], s, c), 0.f);
      *(float4*)(hA + hq(lr, ty)) = r;
    }
    __syncthreads();
    // L3 partial: facc += chunk^T @ W3[jc*64 .. jc*64+63]
    #pragma unroll 4
    for (int k = 0; k < 64; ++k) {
      const float4 hv = *(const float4*)(hA + hq(k, ty));
      const float4 wv = *(const float4*)(W3 + (jc * 64 + k) * 64 + tx * 4);
      FMA16(facc, hv, wv);
    }
  }

  // ---- scatter-max epilogue (ordered-u32 atomicMax) ----
  #pragma unroll
  for (int j = 0; j < 4; ++j) {
    const int sg = seg_s[ty * 4 + j];
    if (sg < 0) continue;
    unsigned* op = out + (size_t)sg * 64 + tx * 4;
    #pragma unroll
    for (int i = 0; i < 4; ++i) {
      atomicMax(op + i, fenc(facc[j][i] + bb3[tx * 4 + i]));
    }
  }
}

extern "C" void kernel_launch(void* const* d_in, const int* in_sizes, int n_in,
                              void* d_out, int out_size, void* d_ws, size_t ws_size,
                              hipStream_t stream) {
  const float* pt_fea = (const float*)d_in[0];
  const int*   pt_ind = (const int*)d_in[1];
  const float* g0  = (const float*)d_in[2];
  const float* bB0 = (const float*)d_in[3];
  const float* m0  = (const float*)d_in[4];
  const float* v0  = (const float*)d_in[5];
  const float* g1  = (const float*)d_in[6];
  const float* bB1 = (const float*)d_in[7];
  const float* m1  = (const float*)d_in[8];
  const float* v1  = (const float*)d_in[9];
  const float* g2  = (const float*)d_in[10];
  const float* bB2 = (const float*)d_in[11];
  const float* m2  = (const float*)d_in[12];
  const float* v2  = (const float*)d_in[13];
  const float* g3  = (const float*)d_in[14];
  const float* bB3 = (const float*)d_in[15];
  const float* m3  = (const float*)d_in[16];
  const float* v3  = (const float*)d_in[17];
  const float* W0  = (const float*)d_in[18];
  const float* bb0 = (const float*)d_in[19];
  const float* W1  = (const float*)d_in[20];
  const float* bb1 = (const float*)d_in[21];
  const float* W2  = (const float*)d_in[22];
  const float* bb2 = (const float*)d_in[23];
  const float* W3  = (const float*)d_in[24];
  const float* bb3 = (const float*)d_in[25];

  const int n4 = NSc * 64 / 4;   // 8388608 uint4
  hipLaunchKernelGGL(init_out_kernel, dim3(4096), dim3(256), 0, stream,
                     (uint4*)d_out, n4);

  const int nblk = (Pc + 63) / 64;   // 7813 blocks of 64 points
  hipLaunchKernelGGL(fused_mlp_kernel, dim3(nblk), dim3(256), 0, stream,
                     pt_fea, pt_ind,
                     g0, bB0, m0, v0, g1, bB1, m1, v1,
                     g2, bB2, m2, v2, g3, bB3, m3, v3,
                     W0, bb0, W1, bb1, W2, bb2, W3, bb3,
                     (unsigned*)d_out);

  hipLaunchKernelGGL(decode_out_kernel, dim3(4096), dim3(256), 0, stream,
                     (uint4*)d_out, n4);
}

// Round 2
// 469.192 us; speedup vs baseline: 2.4610x; 2.4610x over previous
//
#include <hip/hip_runtime.h>

// CylinderFeatureEncoder: BN-folded 4-layer MLP on MFMA (split-bf16 hi/lo, 3-term)
// + voxel scatter-max. Matrix-pipe floor ~85us for the GEMM chain.

using bf16x8 = __attribute__((ext_vector_type(8))) short;  // 8 bf16 = 4 VGPR
using f32x4  = __attribute__((ext_vector_type(4))) float;

constexpr int Bc = 2, Nc = 250000, Pc = 500000, Gc = 64, NSc = 524288;
constexpr float EPSV = 1e-5f;
// ws layout: [0,2048) bytes = cbias f32[512]; then ushort weight planes:
constexpr int W0E = 0;       // 4 frag-pairs  (A-layout, K padded 3->32)
constexpr int W1E = 4096;    // 16 frag-pairs (A-layout)
constexpr int W2E = 20480;   // 64 frag-pairs (A-layout)
constexpr int W3E = 86016;   // 32 frag-pairs (B-layout)
constexpr int CB_BYTES = 2048;

#define MFMA __builtin_amdgcn_mfma_f32_16x16x32_bf16

__device__ __forceinline__ bf16x8 mk8(unsigned a, unsigned b, unsigned c, unsigned d) {
  union { unsigned u[4]; bf16x8 v; } x;
  x.u[0] = a; x.u[1] = b; x.u[2] = c; x.u[3] = d;
  return x.v;
}

__device__ __forceinline__ void gload16(const unsigned short* src, unsigned short* dst_lds) {
  __builtin_amdgcn_global_load_lds(
      (const __attribute__((address_space(1))) unsigned int*)(const void*)src,
      (__attribute__((address_space(3))) unsigned int*)(void*)dst_lds, 16, 0, 0);
}

// ---- ordered-u32 float encoding for atomic max (0u == empty sentinel) ----
__device__ __forceinline__ unsigned fenc(float f) {
  unsigned b = __float_as_uint(f);
  return (b & 0x80000000u) ? ~b : (b | 0x80000000u);
}
__device__ __forceinline__ unsigned fdec(unsigned u) {
  if (u == 0u) return 0u;
  return (u & 0x80000000u) ? (u & 0x7fffffffu) : ~u;
}

__global__ void init_out_kernel(uint4* __restrict__ p, int n4) {
  int i = blockIdx.x * blockDim.x + threadIdx.x;
  const int st = gridDim.x * blockDim.x;
  const uint4 z = make_uint4(0u, 0u, 0u, 0u);
  for (; i < n4; i += st) p[i] = z;
}

__global__ void decode_out_kernel(uint4* __restrict__ p, int n4) {
  int i = blockIdx.x * blockDim.x + threadIdx.x;
  const int st = gridDim.x * blockDim.x;
  for (; i < n4; i += st) {
    uint4 u = p[i];
    u.x = fdec(u.x); u.y = fdec(u.y); u.z = fdec(u.z); u.w = fdec(u.w);
    p[i] = u;
  }
}

// ---- prep: fold BN scales into weights, split to bf16 hi/lo, frag-order ----
__global__ void prep_kernel(
    const float* __restrict__ G0, const float* __restrict__ B0, const float* __restrict__ M0, const float* __restrict__ V0,
    const float* __restrict__ G1, const float* __restrict__ B1, const float* __restrict__ M1, const float* __restrict__ V1,
    const float* __restrict__ G2, const float* __restrict__ B2, const float* __restrict__ M2, const float* __restrict__ V2,
    const float* __restrict__ G3, const float* __restrict__ B3, const float* __restrict__ M3, const float* __restrict__ V3,
    const float* __restrict__ W0, const float* __restrict__ bb0,
    const float* __restrict__ W1, const float* __restrict__ bb1,
    const float* __restrict__ W2, const float* __restrict__ bb2,
    const float* __restrict__ W3, const float* __restrict__ bb3,
    float* __restrict__ cb, unsigned short* __restrict__ wsu)
{
  const int i = blockIdx.x * 256 + threadIdx.x;
  if (i < 59392) {
    const int u = i >> 9, pos = i & 511;
    const int lane = pos >> 3, j = pos & 7;
    const int row16 = lane & 15, kin = (lane >> 4) * 8 + j;
    float v; int dstbase;
    if (u < 4) {                                  // W0f: fold t0 (in) and t1 (out)
      const int mt = u, fo = mt * 16 + row16, k = kin;
      const float t1 = G1[fo] * rsqrtf(V1[fo] + EPSV);
      v = (k < 3) ? (G0[k] * rsqrtf(V0[k] + EPSV)) * W0[k * 64 + fo] * t1 : 0.f;
      dstbase = W0E + u * 1024;
    } else if (u < 20) {                          // W1f: fold t2
      const int q = u - 4, mt = q >> 1, kt = q & 1;
      const int fo = mt * 16 + row16, k = kt * 32 + kin;
      v = W1[k * 128 + fo] * (G2[fo] * rsqrtf(V2[fo] + EPSV));
      dstbase = W1E + q * 1024;
    } else if (u < 84) {                          // W2f: fold t3
      const int q = u - 20, mt = q >> 2, kt = q & 3;
      const int fo = mt * 16 + row16, k = kt * 32 + kin;
      v = W2[k * 256 + fo] * (G3[fo] * rsqrtf(V3[fo] + EPSV));
      dstbase = W2E + q * 1024;
    } else {                                      // W3f: B-layout, no fold
      const int q = u - 84, kt = q >> 2, nt = q & 3;
      const int k = kt * 32 + kin, fo = nt * 16 + row16;
      v = W3[k * 64 + fo];
      dstbase = W3E + q * 1024;
    }
    const unsigned uh = __float_as_uint(v) & 0xffff0000u;
    const float lo = v - __uint_as_float(uh);
    wsu[dstbase + pos]       = (unsigned short)(uh >> 16);
    wsu[dstbase + 512 + pos] = (unsigned short)(__float_as_uint(lo) >> 16);
  } else if (i < 59904) {
    const int f = i - 59392;
    if (f < 64) {
      const int fo = f;
      const float t1 = G1[fo] * rsqrtf(V1[fo] + EPSV);
      float s = 0.f;
      for (int c = 0; c < 3; ++c) {
        const float t0 = G0[c] * rsqrtf(V0[c] + EPSV);
        s += (B0[c] - M0[c] * t0) * W0[c * 64 + fo];
      }
      cb[fo] = (bb0[fo] + s - M1[fo]) * t1 + B1[fo];
    } else if (f < 192) {
      const int fo = f - 64;
      const float t2 = G2[fo] * rsqrtf(V2[fo] + EPSV);
      cb[64 + fo] = (bb1[fo] - M2[fo]) * t2 + B2[fo];
    } else if (f < 448) {
      const int fo = f - 192;
      const float t3 = G3[fo] * rsqrtf(V3[fo] + EPSV);
      cb[192 + fo] = (bb2[fo] - M3[fo]) * t3 + B3[fo];
    } else {
      const int fo = f - 448;
      cb[448 + fo] = bb3[fo];
    }
  }
}

// ---- epilogue: bias + relu + split to packed bf16 hi/lo pairs ----
struct PKp { unsigned h0, h1, l0, l1; };

__device__ __forceinline__ PKp epi_relu(f32x4 d, f32x4 cbv) {
  const float e0 = fmaxf(d[0] + cbv[0], 0.f), e1 = fmaxf(d[1] + cbv[1], 0.f);
  const float e2 = fmaxf(d[2] + cbv[2], 0.f), e3 = fmaxf(d[3] + cbv[3], 0.f);
  const unsigned u0 = __float_as_uint(e0) & 0xffff0000u, u1 = __float_as_uint(e1) & 0xffff0000u;
  const unsigned u2 = __float_as_uint(e2) & 0xffff0000u, u3 = __float_as_uint(e3) & 0xffff0000u;
  PKp r;
  r.h0 = (u0 >> 16) | u1;
  r.h1 = (u2 >> 16) | u3;
  const float f0 = e0 - __uint_as_float(u0), f1 = e1 - __uint_as_float(u1);
  const float f2 = e2 - __uint_as_float(u2), f3 = e3 - __uint_as_float(u3);
  r.l0 = (__float_as_uint(f0) >> 16) | (__float_as_uint(f1) & 0xffff0000u);
  r.l1 = (__float_as_uint(f2) >> 16) | (__float_as_uint(f3) & 0xffff0000u);
  return r;
}

// ---- D-tiles (2K, 2K+1) -> next-layer B-frag for k-tile K ----
// target: lane l, vgpr v holds bf16 pair (k=K*32+8g+2v, +1), col=l&15, g=l>>4
// source: D row r=8(g&1)+2v of tile 2K+(g>>1): lane (2(g&1)+(v>>1))<<4 | col, half v&1
__device__ __forceinline__ void trans2(const PKp& A, const PKp& B, int lane,
                                       bf16x8& fh, bf16x8& fl) {
  const int idx0 = ((lane & 15) << 2) | (((lane >> 4) & 1) << 7);
  const int idx1 = idx0 + 64;
  const bool hi = lane >= 32;
  unsigned v0, v1, v2, v3;
  { unsigned a = __builtin_amdgcn_ds_bpermute(idx0, (int)A.h0), b = __builtin_amdgcn_ds_bpermute(idx0, (int)B.h0); v0 = hi ? b : a; }
  { unsigned a = __builtin_amdgcn_ds_bpermute(idx0, (int)A.h1), b = __builtin_amdgcn_ds_bpermute(idx0, (int)B.h1); v1 = hi ? b : a; }
  { unsigned a = __builtin_amdgcn_ds_bpermute(idx1, (int)A.h0), b = __builtin_amdgcn_ds_bpermute(idx1, (int)B.h0); v2 = hi ? b : a; }
  { unsigned a = __builtin_amdgcn_ds_bpermute(idx1, (int)A.h1), b = __builtin_amdgcn_ds_bpermute(idx1, (int)B.h1); v3 = hi ? b : a; }
  fh = mk8(v0, v1, v2, v3);
  { unsigned a = __builtin_amdgcn_ds_bpermute(idx0, (int)A.l0), b = __builtin_amdgcn_ds_bpermute(idx0, (int)B.l0); v0 = hi ? b : a; }
  { unsigned a = __builtin_amdgcn_ds_bpermute(idx0, (int)A.l1), b = __builtin_amdgcn_ds_bpermute(idx0, (int)B.l1); v1 = hi ? b : a; }
  { unsigned a = __builtin_amdgcn_ds_bpermute(idx1, (int)A.l0), b = __builtin_amdgcn_ds_bpermute(idx1, (int)B.l0); v2 = hi ? b : a; }
  { unsigned a = __builtin_amdgcn_ds_bpermute(idx1, (int)A.l1), b = __builtin_amdgcn_ds_bpermute(idx1, (int)B.l1); v3 = hi ? b : a; }
  fl = mk8(v0, v1, v2, v3);
}

__global__ __launch_bounds__(512, 2)
void mlp_mfma(const float* __restrict__ pt_fea, const int* __restrict__ pt_ind,
              const unsigned short* __restrict__ wsu, const float* __restrict__ cb,
              unsigned* __restrict__ out)
{
  __shared__ __align__(16) unsigned short lds[49152];  // 96KB: W1 [0,16K) u16; bufA [16K,48K) u16

  const int tid = threadIdx.x, lane = tid & 63, wv = tid >> 6;
  const int g = lane >> 4, c16 = lane & 15;
  const int pw = (blockIdx.x * 8 + wv) * 32;   // this wave's 32-point base

  // stage W1 (32 chunks) + W2 m-half0 (64 chunks) via global_load_lds
  #pragma unroll
  for (int c = 0; c < 4; ++c) {
    const int ch = wv * 4 + c;
    gload16(wsu + W1E + ch * 512 + lane * 8, &lds[ch * 512]);
  }
  #pragma unroll
  for (int c = 0; c < 8; ++c) {
    const int ch = wv * 8 + c;
    gload16(wsu + W2E + ch * 512 + lane * 8, &lds[16384 + ch * 512]);
  }

  // ---- L0 (3->64), weights from global (L2-hot) ----
  bf16x8 b0h[2], b0l[2];
  #pragma unroll
  for (int nt = 0; nt < 2; ++nt) {
    const int p = pw + nt * 16 + c16;
    float x = 0.f, y = 0.f, z = 0.f;
    if (p < Pc) { x = pt_fea[p * 3]; y = pt_fea[p * 3 + 1]; z = pt_fea[p * 3 + 2]; }
    const unsigned ux = __float_as_uint(x) & 0xffff0000u;
    const unsigned uy = __float_as_uint(y) & 0xffff0000u;
    const unsigned uz = __float_as_uint(z) & 0xffff0000u;
    const float lx = x - __uint_as_float(ux), ly = y - __uint_as_float(uy), lz = z - __uint_as_float(uz);
    const unsigned ph0 = (ux >> 16) | uy, ph1 = (uz >> 16);
    const unsigned pl0 = (__float_as_uint(lx) >> 16) | (__float_as_uint(ly) & 0xffff0000u);
    const unsigned pl1 = (__float_as_uint(lz) >> 16);
    const bool g0ok = (g == 0);
    b0h[nt] = mk8(g0ok ? ph0 : 0u, g0ok ? ph1 : 0u, 0u, 0u);
    b0l[nt] = mk8(g0ok ? pl0 : 0u, g0ok ? pl1 : 0u, 0u, 0u);
  }

  bf16x8 B1h[2][2], B1l[2][2];  // [kt][nt]
  #pragma unroll
  for (int K = 0; K < 2; ++K) {
    PKp pk[2][2];
    #pragma unroll
    for (int e = 0; e < 2; ++e) {
      const int mt = 2 * K + e;
      const bf16x8 wh = *(const bf16x8*)(wsu + W0E + mt * 1024 + lane * 8);
      const bf16x8 wl = *(const bf16x8*)(wsu + W0E + mt * 1024 + 512 + lane * 8);
      const f32x4 cbv = *(const f32x4*)(cb + mt * 16 + g * 4);
      #pragma unroll
      for (int nt = 0; nt < 2; ++nt) {
        f32x4 acc = {0.f, 0.f, 0.f, 0.f};
        acc = MFMA(wh, b0h[nt], acc, 0, 0, 0);
        acc = MFMA(wh, b0l[nt], acc, 0, 0, 0);
        acc = MFMA(wl, b0h[nt], acc, 0, 0, 0);
        pk[e][nt] = epi_relu(acc, cbv);
      }
    }
    #pragma unroll
    for (int nt = 0; nt < 2; ++nt) trans2(pk[0][nt], pk[1][nt], lane, B1h[K][nt], B1l[K][nt]);
  }

  __syncthreads();  // W1 + W2-half0 staged

  // ---- L1 (64->128), W1 from LDS ----
  bf16x8 B2h[4][2], B2l[4][2];
  #pragma unroll
  for (int K = 0; K < 4; ++K) {
    PKp pk[2][2];
    #pragma unroll
    for (int e = 0; e < 2; ++e) {
      const int mt = 2 * K + e;
      bf16x8 w[2][2];
      #pragma unroll
      for (int kt = 0; kt < 2; ++kt) {
        w[kt][0] = *(const bf16x8*)&lds[(mt * 2 + kt) * 1024 + lane * 8];
        w[kt][1] = *(const bf16x8*)&lds[(mt * 2 + kt) * 1024 + 512 + lane * 8];
      }
      const f32x4 cbv = *(const f32x4*)(cb + 64 + mt * 16 + g * 4);
      #pragma unroll
      for (int nt = 0; nt < 2; ++nt) {
        f32x4 acc = {0.f, 0.f, 0.f, 0.f};
        #pragma unroll
        for (int kt = 0; kt < 2; ++kt) {
          acc = MFMA(w[kt][0], B1h[kt][nt], acc, 0, 0, 0);
          acc = MFMA(w[kt][0], B1l[kt][nt], acc, 0, 0, 0);
          acc = MFMA(w[kt][1], B1h[kt][nt], acc, 0, 0, 0);
        }
        pk[e][nt] = epi_relu(acc, cbv);
      }
    }
    #pragma unroll
    for (int nt = 0; nt < 2; ++nt) trans2(pk[0][nt], pk[1][nt], lane, B2h[K][nt], B2l[K][nt]);
  }

  // ---- L2 (128->256) fused with L3 (256->64, swapped operands) ----
  f32x4 acc3[2][4];
  #pragma unroll
  for (int pm = 0; pm < 2; ++pm)
    #pragma unroll
    for (int n3 = 0; n3 < 4; ++n3) acc3[pm][n3] = (f32x4){0.f, 0.f, 0.f, 0.f};

  float c3v[4];
  #pragma unroll
  for (int n3 = 0; n3 < 4; ++n3) c3v[n3] = cb[448 + n3 * 16 + c16];

  #pragma unroll 1
  for (int half = 0; half < 2; ++half) {
    if (half == 1) {
      __syncthreads();  // all waves done reading bufA
      #pragma unroll
      for (int c = 0; c < 8; ++c) {
        const int ch = wv * 8 + c;
        gload16(wsu + W2E + 32768 + ch * 512 + lane * 8, &lds[16384 + ch * 512]);
      }
      __syncthreads();  // half1 staged
    }
    #pragma unroll 1
    for (int Kl = 0; Kl < 4; ++Kl) {
      const int K = half * 4 + Kl;
      PKp pk[2][2];
      #pragma unroll
      for (int e = 0; e < 2; ++e) {
        const int mtl = 2 * Kl + e;            // local m-tile in bufA
        const int mt = half * 8 + mtl;         // global L2 m-tile
        bf16x8 w[4][2];
        #pragma unroll
        for (int kt = 0; kt < 4; ++kt) {
          w[kt][0] = *(const bf16x8*)&lds[16384 + (mtl * 4 + kt) * 1024 + lane * 8];
          w[kt][1] = *(const bf16x8*)&lds[16384 + (mtl * 4 + kt) * 1024 + 512 + lane * 8];
        }
        const f32x4 cbv = *(const f32x4*)(cb + 192 + mt * 16 + g * 4);
        #pragma unroll
        for (int nt = 0; nt < 2; ++nt) {
          f32x4 acc = {0.f, 0.f, 0.f, 0.f};
          #pragma unroll
          for (int kt = 0; kt < 4; ++kt) {
            acc = MFMA(w[kt][0], B2h[kt][nt], acc, 0, 0, 0);
            acc = MFMA(w[kt][0], B2l[kt][nt], acc, 0, 0, 0);
            acc = MFMA(w[kt][1], B2h[kt][nt], acc, 0, 0, 0);
          }
          pk[e][nt] = epi_relu(acc, cbv);
        }
      }
      // W3 frags for this k-tile (global, L2-hot), reused across both point-tiles
      bf16x8 w3[4][2];
      #pragma unroll
      for (int n3 = 0; n3 < 4; ++n3) {
        w3[n3][0] = *(const bf16x8*)(wsu + W3E + (K * 4 + n3) * 1024 + lane * 8);
        w3[n3][1] = *(const bf16x8*)(wsu + W3E + (K * 4 + n3) * 1024 + 512 + lane * 8);
      }
      #pragma unroll
      for (int nt = 0; nt < 2; ++nt) {
        bf16x8 a3h, a3l;
        trans2(pk[0][nt], pk[1][nt], lane, a3h, a3l);
        #pragma unroll
        for (int n3 = 0; n3 < 4; ++n3) {
          acc3[nt][n3] = MFMA(a3h, w3[n3][0], acc3[nt][n3], 0, 0, 0);
          acc3[nt][n3] = MFMA(a3l, w3[n3][0], acc3[nt][n3], 0, 0, 0);
          acc3[nt][n3] = MFMA(a3h, w3[n3][1], acc3[nt][n3], 0, 0, 0);
        }
      }
    }
  }

  // ---- scatter-max epilogue: D3 row=point (4g+j within tile), col=f3out ----
  #pragma unroll
  for (int pm = 0; pm < 2; ++pm) {
    #pragma unroll
    for (int j = 0; j < 4; ++j) {
      const int p = pw + pm * 16 + g * 4 + j;
      if (p < Pc) {
        const int ix = pt_ind[p * 3], iy = pt_ind[p * 3 + 1], iz = pt_ind[p * 3 + 2];
        const int b = (p >= Nc) ? 1 : 0;
        const unsigned seg = ((unsigned)(b * Gc + iz) * Gc + iy) * Gc + ix;
        unsigned* op = out + (size_t)seg * 64 + c16;
        #pragma unroll
        for (int n3 = 0; n3 < 4; ++n3) {
          atomicMax(op + n3 * 16, fenc(acc3[pm][n3][j] + c3v[n3]));
        }
      }
    }
  }
}

extern "C" void kernel_launch(void* const* d_in, const int* in_sizes, int n_in,
                              void* d_out, int out_size, void* d_ws, size_t ws_size,
                              hipStream_t stream) {
  const float* pt_fea = (const float*)d_in[0];
  const int*   pt_ind = (const int*)d_in[1];

  float* cb = (float*)d_ws;
  unsigned short* wsu = (unsigned short*)((char*)d_ws + CB_BYTES);

  hipLaunchKernelGGL(prep_kernel, dim3(234), dim3(256), 0, stream,
                     (const float*)d_in[2],  (const float*)d_in[3],  (const float*)d_in[4],  (const float*)d_in[5],
                     (const float*)d_in[6],  (const float*)d_in[7],  (const float*)d_in[8],  (const float*)d_in[9],
                     (const float*)d_in[10], (const float*)d_in[11], (const float*)d_in[12], (const float*)d_in[13],
                     (const float*)d_in[14], (const float*)d_in[15], (const float*)d_in[16], (const float*)d_in[17],
                     (const float*)d_in[18], (const float*)d_in[19], (const float*)d_in[20], (const float*)d_in[21],
                     (const float*)d_in[22], (const float*)d_in[23], (const float*)d_in[24], (const float*)d_in[25],
                     cb, wsu);

  const int n4 = NSc * 64 / 4;
  hipLaunchKernelGGL(init_out_kernel, dim3(4096), dim3(256), 0, stream, (uint4*)d_out, n4);

  const int nblk = (Pc / 32 + 7) / 8;  // 1954 blocks of 8 waves x 32 points
  hipLaunchKernelGGL(mlp_mfma, dim3(nblk), dim3(512), 0, stream,
                     pt_fea, pt_ind, wsu, cb, (unsigned*)d_out);

  hipLaunchKernelGGL(decode_out_kernel, dim3(4096), dim3(256), 0, stream, (uint4*)d_out, n4);
}